// Round 1
// baseline (1089.013 us; speedup 1.0000x reference)
//
#include <hip/hip_runtime.h>
#include <math.h>

#define HD 128
#define WD 128
#define HW (HD*WD)

// ---------------------------------------------------------------------------
// Kernel 0: transpose w_real/w_imag (Cout=64, C=64, K=9) -> [k][c][o]
// ---------------------------------------------------------------------------
__global__ __launch_bounds__(256) void k_transpose_w(
    const float* __restrict__ w_real, const float* __restrict__ w_imag,
    float* __restrict__ wrT, float* __restrict__ wiT) {
  int t = blockIdx.x * 256 + threadIdx.x;
  if (t >= 64 * 64 * 9) return;
  int o = t & 63;
  int c = (t >> 6) & 63;
  int k = t >> 12;
  wrT[t] = w_real[(o * 64 + c) * 9 + k];
  wiT[t] = w_imag[(o * 64 + c) * 9 + k];
}

// ---------------------------------------------------------------------------
// Kernel 1: offset conv (128ch -> 18ch) + magnitude conv (64ch -> 9ch, sigmoid)
// One thread per output pixel.
// ---------------------------------------------------------------------------
__global__ __launch_bounds__(256) void k_offmag(
    const float* __restrict__ xr, const float* __restrict__ xi,
    const float* __restrict__ w_off, const float* __restrict__ w_mag,
    float* __restrict__ off_o, float* __restrict__ mag_o) {
  int pix = blockIdx.x * 256 + threadIdx.x;   // 0 .. 131071
  int w = pix & (WD - 1);
  int h = (pix >> 7) & (HD - 1);
  int b = pix >> 14;
  const float* xrb = xr + (size_t)b * 64 * HW;
  const float* xib = xi + (size_t)b * 64 * HW;

  float ao[18];
  float am[9];
#pragma unroll
  for (int i = 0; i < 18; ++i) ao[i] = 0.f;
#pragma unroll
  for (int i = 0; i < 9; ++i) am[i] = 0.f;

#pragma unroll 1
  for (int c = 0; c < 64; ++c) {
    float vr[9], vi[9], vm[9];
#pragma unroll
    for (int t = 0; t < 9; ++t) {
      int y = h + t / 3 - 1;
      int x = w + t % 3 - 1;
      bool ok = ((unsigned)y < (unsigned)HD) && ((unsigned)x < (unsigned)WD);
      int yc = y < 0 ? 0 : (y > HD - 1 ? HD - 1 : y);
      int xc = x < 0 ? 0 : (x > WD - 1 ? WD - 1 : x);
      int idx = c * HW + yc * WD + xc;
      float m = ok ? 1.f : 0.f;
      float r = xrb[idx] * m;
      float q = xib[idx] * m;
      vr[t] = r;
      vi[t] = q;
      vm[t] = sqrtf(r * r + q * q);
    }
    // offset conv: input channel c (real part) and c+64 (imag part)
#pragma unroll
    for (int oc = 0; oc < 18; ++oc) {
      const float* wr = w_off + ((size_t)oc * 128 + c) * 9;
      const float* wq = w_off + ((size_t)oc * 128 + 64 + c) * 9;
      float a = ao[oc];
#pragma unroll
      for (int t = 0; t < 9; ++t) a += wr[t] * vr[t];
#pragma unroll
      for (int t = 0; t < 9; ++t) a += wq[t] * vi[t];
      ao[oc] = a;
    }
    // magnitude conv
#pragma unroll
    for (int oc = 0; oc < 9; ++oc) {
      const float* wm = w_mag + ((size_t)oc * 64 + c) * 9;
      float a = am[oc];
#pragma unroll
      for (int t = 0; t < 9; ++t) a += wm[t] * vm[t];
      am[oc] = a;
    }
  }

  int ppos = h * WD + w;
#pragma unroll
  for (int oc = 0; oc < 18; ++oc)
    off_o[((size_t)(b * 18 + oc)) * HW + ppos] = ao[oc];
#pragma unroll
  for (int oc = 0; oc < 9; ++oc) {
    float s = 1.f / (1.f + expf(-am[oc]));
    mag_o[((size_t)(b * 9 + oc)) * HW + ppos] = s;
  }
}

// ---------------------------------------------------------------------------
// Kernel 2: fused deformable sampling + complex contraction.
// Block = 64 consecutive pixels of one (b,h) row-half; 256 threads = 4 waves.
// Wave g owns output channels [16g, 16g+16); lane = pixel.
// Loop k in 0..8: sample S[128c][64pix] (mag folded into bilinear weights)
// into LDS, then accumulate real/imag via transposed weights [k][c][o].
// ---------------------------------------------------------------------------
__global__ __launch_bounds__(256) void k_main(
    const float* __restrict__ xr, const float* __restrict__ xi,
    const float* __restrict__ off_i, const float* __restrict__ mag_i,
    const float* __restrict__ wrT, const float* __restrict__ wiT,
    const float* __restrict__ b_real, const float* __restrict__ b_imag,
    float* __restrict__ out) {
  __shared__ float S[128 * 64];   // 32 KB

  int blk = blockIdx.x;           // 0 .. 2047
  int wt = blk & 1;
  int h = (blk >> 1) & (HD - 1);
  int b = blk >> 8;
  int w0 = wt * 64;

  int tid = threadIdx.x;
  int lane = tid & 63;
  int grp = tid >> 6;             // 0..3
  int w = w0 + lane;

  const float* xrb = xr + (size_t)b * 64 * HW;
  const float* xib = xi + (size_t)b * 64 * HW;
  int obase = __builtin_amdgcn_readfirstlane(grp * 16);

  float accR[16], accI[16];
#pragma unroll
  for (int j = 0; j < 16; ++j) { accR[j] = 0.f; accI[j] = 0.f; }

  int ppos = h * WD + w;

#pragma unroll 1
  for (int k = 0; k < 9; ++k) {
    // ---- per-pixel corner data (each wave recomputes; cheap) ----
    float dy = off_i[((size_t)(b * 18 + 2 * k)) * HW + ppos];
    float dx = off_i[((size_t)(b * 18 + 2 * k + 1)) * HW + ppos];
    float m  = mag_i[((size_t)(b * 9 + k)) * HW + ppos];
    float py = (float)(h - 1 + k / 3) + dy;
    float px = (float)(w - 1 + k % 3) + dx;
    float y0f = floorf(py), x0f = floorf(px);
    float wy = py - y0f, wx = px - x0f;
    int y0 = (int)y0f, x0 = (int)x0f;

    float cw[4];
    cw[0] = (1.f - wy) * (1.f - wx) * m;
    cw[1] = (1.f - wy) * wx * m;
    cw[2] = wy * (1.f - wx) * m;
    cw[3] = wy * wx * m;
    int idx[4];
#pragma unroll
    for (int cc = 0; cc < 4; ++cc) {
      int yy = y0 + (cc >> 1);
      int xx = x0 + (cc & 1);
      bool ok = ((unsigned)yy < (unsigned)HD) && ((unsigned)xx < (unsigned)WD);
      if (!ok) cw[cc] = 0.f;
      int yc = yy < 0 ? 0 : (yy > HD - 1 ? HD - 1 : yy);
      int xc = xx < 0 ? 0 : (xx > WD - 1 ? WD - 1 : xx);
      idx[cc] = yc * WD + xc;
    }

    // ---- sampling: this thread covers 32 channels at its pixel ----
    int cbase = grp * 32;
    const float* xbase = (cbase < 64) ? xrb : (xib - (size_t)64 * HW);
#pragma unroll 4
    for (int j = 0; j < 32; ++j) {
      int c = cbase + j;
      const float* p = xbase + (size_t)c * HW;
      float v = cw[0] * p[idx[0]] + cw[1] * p[idx[1]] +
                cw[2] * p[idx[2]] + cw[3] * p[idx[3]];
      S[c * 64 + lane] = v;
    }
    __syncthreads();

    // ---- contraction for this k ----
    const float* wrk = wrT + (size_t)k * 4096;   // [c][o]
    const float* wik = wiT + (size_t)k * 4096;
#pragma unroll 2
    for (int c = 0; c < 64; ++c) {
      float sr = S[c * 64 + lane];
      float si = S[(c + 64) * 64 + lane];
      const float* wr_ = wrk + c * 64 + obase;
      const float* wi_ = wik + c * 64 + obase;
#pragma unroll
      for (int j = 0; j < 16; ++j) {
        float wr = wr_[j];
        float wi = wi_[j];
        accR[j] += wr * sr - wi * si;
        accI[j] += wi * sr - wr * si;
      }
    }
    __syncthreads();
  }

  // ---- epilogue: bias + interleaved store (real, imag) ----
  float2* outp = (float2*)out;
#pragma unroll
  for (int j = 0; j < 16; ++j) {
    int o = obase + j;
    float br = b_real[o] - b_imag[o];
    float2 v;
    v.x = accR[j] + br;
    v.y = accI[j] - br;
    outp[((size_t)(b * 64 + o)) * HW + ppos] = v;
  }
}

// ---------------------------------------------------------------------------
extern "C" void kernel_launch(void* const* d_in, const int* in_sizes, int n_in,
                              void* d_out, int out_size, void* d_ws, size_t ws_size,
                              hipStream_t stream) {
  const float* xr     = (const float*)d_in[0];
  const float* xi     = (const float*)d_in[1];
  const float* w_off  = (const float*)d_in[2];
  const float* w_mag  = (const float*)d_in[3];
  const float* w_real = (const float*)d_in[4];
  const float* w_imag = (const float*)d_in[5];
  const float* b_real = (const float*)d_in[6];
  const float* b_imag = (const float*)d_in[7];
  float* out = (float*)d_out;

  float* ws = (float*)d_ws;
  float* off_ws = ws;                            // 8*18*16384 = 2359296 floats
  float* mag_ws = off_ws + 2359296;              // 8*9*16384  = 1179648 floats
  float* wrT    = mag_ws + 1179648;              // 36864 floats
  float* wiT    = wrT + 36864;                   // 36864 floats
  // total ws use: 3612672 floats = 14.45 MB

  hipLaunchKernelGGL(k_transpose_w, dim3(144), dim3(256), 0, stream,
                     w_real, w_imag, wrT, wiT);
  hipLaunchKernelGGL(k_offmag, dim3(512), dim3(256), 0, stream,
                     xr, xi, w_off, w_mag, off_ws, mag_ws);
  hipLaunchKernelGGL(k_main, dim3(2048), dim3(256), 0, stream,
                     xr, xi, off_ws, mag_ws, wrT, wiT, b_real, b_imag, out);
}

// Round 2
// 740.733 us; speedup vs baseline: 1.4702x; 1.4702x over previous
//
#include <hip/hip_runtime.h>
#include <math.h>

#define HD 128
#define WD 128
#define HW (HD*WD)

typedef __attribute__((ext_vector_type(8))) short s16x8;     // 8 bf16 (4 VGPRs)
typedef __attribute__((ext_vector_type(4))) float f32x4;     // MFMA acc
typedef __attribute__((ext_vector_type(4))) unsigned int u32x4;

// round-to-nearest-even f32 -> bf16 bits, packed pair
__device__ inline unsigned int pkbf(float a, float b) {
  unsigned int ua = __builtin_bit_cast(unsigned int, a);
  unsigned int ub = __builtin_bit_cast(unsigned int, b);
  ua = (ua + 0x7fffu + ((ua >> 16) & 1u)) >> 16;
  ub = (ub + 0x7fffu + ((ub >> 16) & 1u)) >> 16;
  return ua | (ub << 16);
}

// ---------------------------------------------------------------------------
// Kernel 0: build Wcomb[9][128][128] bf16.  Row r (out), col c (in):
//   r<64 :  c<64 ? Wr[r][c][k]    : -Wi[r][c-64][k]      (real output rows)
//   r>=64:  c<64 ? Wi[r-64][c][k] : -Wr[r-64][c-64][k]   (imag output rows)
// ---------------------------------------------------------------------------
__global__ __launch_bounds__(256) void k_prepw(
    const float* __restrict__ wr, const float* __restrict__ wi,
    unsigned short* __restrict__ wc) {
  int t = blockIdx.x * 256 + threadIdx.x;
  if (t >= 9 * 128 * 128) return;
  int c = t & 127;
  int r = (t >> 7) & 127;
  int k = t >> 14;
  float v;
  if (r < 64) v = (c < 64) ? wr[(r * 64 + c) * 9 + k] : -wi[(r * 64 + c - 64) * 9 + k];
  else {
    int r2 = r - 64;
    v = (c < 64) ? wi[(r2 * 64 + c) * 9 + k] : -wr[(r2 * 64 + c - 64) * 9 + k];
  }
  unsigned int u = __builtin_bit_cast(unsigned int, v);
  u = (u + 0x7fffu + ((u >> 16) & 1u)) >> 16;
  wc[t] = (unsigned short)u;
}

// ---------------------------------------------------------------------------
// Kernel 1: offset conv (128ch -> 18ch) + magnitude conv (64ch -> 9ch, sigmoid)
// ---------------------------------------------------------------------------
__global__ __launch_bounds__(256) void k_offmag(
    const float* __restrict__ xr, const float* __restrict__ xi,
    const float* __restrict__ w_off, const float* __restrict__ w_mag,
    float* __restrict__ off_o, float* __restrict__ mag_o) {
  int pix = blockIdx.x * 256 + threadIdx.x;
  int w = pix & (WD - 1);
  int h = (pix >> 7) & (HD - 1);
  int b = pix >> 14;
  const float* xrb = xr + (size_t)b * 64 * HW;
  const float* xib = xi + (size_t)b * 64 * HW;

  float ao[18];
  float am[9];
#pragma unroll
  for (int i = 0; i < 18; ++i) ao[i] = 0.f;
#pragma unroll
  for (int i = 0; i < 9; ++i) am[i] = 0.f;

#pragma unroll 1
  for (int c = 0; c < 64; ++c) {
    float vr[9], vi[9], vm[9];
#pragma unroll
    for (int t = 0; t < 9; ++t) {
      int y = h + t / 3 - 1;
      int x = w + t % 3 - 1;
      bool ok = ((unsigned)y < (unsigned)HD) && ((unsigned)x < (unsigned)WD);
      int yc = y < 0 ? 0 : (y > HD - 1 ? HD - 1 : y);
      int xc = x < 0 ? 0 : (x > WD - 1 ? WD - 1 : x);
      int idx = c * HW + yc * WD + xc;
      float m = ok ? 1.f : 0.f;
      float r = xrb[idx] * m;
      float q = xib[idx] * m;
      vr[t] = r;
      vi[t] = q;
      vm[t] = sqrtf(r * r + q * q);
    }
#pragma unroll
    for (int oc = 0; oc < 18; ++oc) {
      const float* wrp = w_off + ((size_t)oc * 128 + c) * 9;
      const float* wqp = w_off + ((size_t)oc * 128 + 64 + c) * 9;
      float a = ao[oc];
#pragma unroll
      for (int t = 0; t < 9; ++t) a += wrp[t] * vr[t];
#pragma unroll
      for (int t = 0; t < 9; ++t) a += wqp[t] * vi[t];
      ao[oc] = a;
    }
#pragma unroll
    for (int oc = 0; oc < 9; ++oc) {
      const float* wm = w_mag + ((size_t)oc * 64 + c) * 9;
      float a = am[oc];
#pragma unroll
      for (int t = 0; t < 9; ++t) a += wm[t] * vm[t];
      am[oc] = a;
    }
  }

  int ppos = h * WD + w;
#pragma unroll
  for (int oc = 0; oc < 18; ++oc)
    off_o[((size_t)(b * 18 + oc)) * HW + ppos] = ao[oc];
#pragma unroll
  for (int oc = 0; oc < 9; ++oc) {
    float s = 1.f / (1.f + expf(-am[oc]));
    mag_o[((size_t)(b * 9 + oc)) * HW + ppos] = s;
  }
}

// ---------------------------------------------------------------------------
// Kernel 2: deformable sampling + complex contraction via bf16 MFMA.
// Block = 64 pixels (half row). 4 waves. Per tap k:
//   sample S_T[pix][128 c] bf16 into LDS (XOR-swizzled rows, stride 256B),
//   GEMM: Wcomb[128 out][128 c] x S[128 c][64 pix] via 16x16x32 MFMA.
// Wave g owns out rows [16g,16g+16) real (mtile g) + imag (mtile g+4).
// ---------------------------------------------------------------------------
__global__ __launch_bounds__(256) void k_main(
    const float* __restrict__ xr, const float* __restrict__ xi,
    const float* __restrict__ off_i, const float* __restrict__ mag_i,
    const unsigned short* __restrict__ Wc,
    const float* __restrict__ b_real, const float* __restrict__ b_imag,
    float* __restrict__ out) {
  __shared__ unsigned short S[64 * 128];   // 16 KB

  int blk = blockIdx.x;
  int wt = blk & 1;
  int h = (blk >> 1) & (HD - 1);
  int b = blk >> 8;
  int w0 = wt * 64;

  int tid = threadIdx.x;
  int lane = tid & 63;
  int g = tid >> 6;               // wave id 0..3
  int w = w0 + lane;              // this thread's sampling pixel
  int l15 = lane & 15;
  int hi8 = (lane >> 4) * 8;      // k-offset within fragment
  int xo = (l15 & 7) << 4;        // read-side XOR (row = tile*16 + l15)

  const float* xrb = xr + (size_t)b * 64 * HW;
  const float* xib = xi + (size_t)b * 64 * HW;
  int cbase = g * 32;             // channels this thread samples
  const float* xbase = (g < 2) ? (xrb + (size_t)cbase * HW)
                               : (xib + (size_t)(cbase - 64) * HW);
  int ppos = h * WD + w;

  f32x4 accR[4], accI[4];
#pragma unroll
  for (int t = 0; t < 4; ++t) {
    accR[t] = (f32x4)(0.f);
    accI[t] = (f32x4)(0.f);
  }

#pragma unroll 1
  for (int k = 0; k < 9; ++k) {
    // ---- per-pixel bilinear corner data ----
    float dy = off_i[((size_t)(b * 18 + 2 * k)) * HW + ppos];
    float dx = off_i[((size_t)(b * 18 + 2 * k + 1)) * HW + ppos];
    float m  = mag_i[((size_t)(b * 9 + k)) * HW + ppos];
    float py = (float)(h - 1 + k / 3) + dy;
    float px = (float)(w - 1 + k % 3) + dx;
    float y0f = floorf(py), x0f = floorf(px);
    float wy = py - y0f, wx = px - x0f;
    int y0 = (int)y0f, x0 = (int)x0f;

    float cw[4];
    cw[0] = (1.f - wy) * (1.f - wx) * m;
    cw[1] = (1.f - wy) * wx * m;
    cw[2] = wy * (1.f - wx) * m;
    cw[3] = wy * wx * m;
    int idx[4];
#pragma unroll
    for (int cc = 0; cc < 4; ++cc) {
      int yy = y0 + (cc >> 1);
      int xx = x0 + (cc & 1);
      bool ok = ((unsigned)yy < (unsigned)HD) && ((unsigned)xx < (unsigned)WD);
      if (!ok) cw[cc] = 0.f;
      int yc = yy < 0 ? 0 : (yy > HD - 1 ? HD - 1 : yy);
      int xc = xx < 0 ? 0 : (xx > WD - 1 ? WD - 1 : xx);
      idx[cc] = yc * WD + xc;
    }

    // ---- sample 32 channels at this pixel -> bf16 -> swizzled LDS row ----
#pragma unroll
    for (int q = 0; q < 4; ++q) {
      u32x4 wv;
#pragma unroll
      for (int j2 = 0; j2 < 4; ++j2) {
        const float* p0 = xbase + (size_t)(q * 8 + j2 * 2) * HW;
        const float* p1 = p0 + HW;
        float v0 = cw[0] * p0[idx[0]] + cw[1] * p0[idx[1]] +
                   cw[2] * p0[idx[2]] + cw[3] * p0[idx[3]];
        float v1 = cw[0] * p1[idx[0]] + cw[1] * p1[idx[1]] +
                   cw[2] * p1[idx[2]] + cw[3] * p1[idx[3]];
        wv[j2] = pkbf(v0, v1);
      }
      int bytecol = ((cbase + q * 8) * 2) ^ ((lane & 7) << 4);
      *(u32x4*)((char*)S + lane * 256 + bytecol) = wv;
    }

    // ---- A-fragments (weights, L2-hot) — issue before the barrier ----
    const unsigned short* wa = Wc + (size_t)k * 16384 + (g * 16 + l15) * 128 + hi8;
    s16x8 aR[4], aI[4];
#pragma unroll
    for (int s = 0; s < 4; ++s) {
      aR[s] = *(const s16x8*)(wa + s * 32);
      aI[s] = *(const s16x8*)(wa + 64 * 128 + s * 32);
    }

    __syncthreads();

    // ---- MFMA: 4 n-tiles x 4 k-steps, B shared between real/imag ----
#pragma unroll
    for (int t = 0; t < 4; ++t) {
      const char* brow = (const char*)S + (t * 16 + l15) * 256;
#pragma unroll
      for (int s = 0; s < 4; ++s) {
        s16x8 bf = *(const s16x8*)(brow + ((s * 64 + (hi8 << 1)) ^ xo));
        accR[t] = __builtin_amdgcn_mfma_f32_16x16x32_bf16(aR[s], bf, accR[t], 0, 0, 0);
        accI[t] = __builtin_amdgcn_mfma_f32_16x16x32_bf16(aI[s], bf, accI[t], 0, 0, 0);
      }
    }
    __syncthreads();
  }

  // ---- epilogue: bias + coalesced float2 stores ----
  float2* outp = (float2*)out;
#pragma unroll
  for (int r = 0; r < 4; ++r) {
    int o = g * 16 + (lane >> 4) * 4 + r;
    float br = b_real[o] - b_imag[o];
#pragma unroll
    for (int t = 0; t < 4; ++t) {
      int pe = h * WD + w0 + t * 16 + l15;
      float2 v;
      v.x = accR[t][r] + br;
      v.y = accI[t][r] - br;
      outp[((size_t)(b * 64 + o)) * HW + pe] = v;
    }
  }
}

// ---------------------------------------------------------------------------
extern "C" void kernel_launch(void* const* d_in, const int* in_sizes, int n_in,
                              void* d_out, int out_size, void* d_ws, size_t ws_size,
                              hipStream_t stream) {
  const float* xr     = (const float*)d_in[0];
  const float* xi     = (const float*)d_in[1];
  const float* w_off  = (const float*)d_in[2];
  const float* w_mag  = (const float*)d_in[3];
  const float* w_real = (const float*)d_in[4];
  const float* w_imag = (const float*)d_in[5];
  const float* b_real = (const float*)d_in[6];
  const float* b_imag = (const float*)d_in[7];
  float* out = (float*)d_out;

  float* ws = (float*)d_ws;
  float* off_ws = ws;                              // 8*18*16384 = 2359296 f
  float* mag_ws = off_ws + 2359296;                // 8*9*16384  = 1179648 f
  unsigned short* Wc = (unsigned short*)(mag_ws + 1179648); // 9*128*128 bf16

  hipLaunchKernelGGL(k_prepw, dim3(576), dim3(256), 0, stream,
                     w_real, w_imag, Wc);
  hipLaunchKernelGGL(k_offmag, dim3(512), dim3(256), 0, stream,
                     xr, xi, w_off, w_mag, off_ws, mag_ws);
  hipLaunchKernelGGL(k_main, dim3(2048), dim3(256), 0, stream,
                     xr, xi, off_ws, mag_ws, Wc, b_real, b_imag, out);
}

// Round 3
// 621.020 us; speedup vs baseline: 1.7536x; 1.1928x over previous
//
#include <hip/hip_runtime.h>
#include <math.h>

#define HD 128
#define WD 128
#define HW (HD*WD)

typedef __attribute__((ext_vector_type(8))) short s16x8;     // 8 bf16 (4 VGPRs)
typedef __attribute__((ext_vector_type(4))) float f32x4;     // MFMA acc
typedef __attribute__((ext_vector_type(4))) unsigned int u32x4;

// round-to-nearest-even f32 -> bf16 bits, packed pair
__device__ inline unsigned int pkbf(float a, float b) {
  unsigned int ua = __builtin_bit_cast(unsigned int, a);
  unsigned int ub = __builtin_bit_cast(unsigned int, b);
  ua = (ua + 0x7fffu + ((ua >> 16) & 1u)) >> 16;
  ub = (ub + 0x7fffu + ((ub >> 16) & 1u)) >> 16;
  return ua | (ub << 16);
}

// ---------------------------------------------------------------------------
// Kernel 0a: build Wcomb[9][128][128] bf16 for the main contraction.
//   r<64 :  c<64 ? Wr[r][c][k]    : -Wi[r][c-64][k]      (real output rows)
//   r>=64:  c<64 ? Wi[r-64][c][k] : -Wr[r-64][c-64][k]   (imag output rows)
// ---------------------------------------------------------------------------
__global__ __launch_bounds__(256) void k_prepw(
    const float* __restrict__ wr, const float* __restrict__ wi,
    unsigned short* __restrict__ wc) {
  int t = blockIdx.x * 256 + threadIdx.x;
  if (t >= 9 * 128 * 128) return;
  int c = t & 127;
  int r = (t >> 7) & 127;
  int k = t >> 14;
  float v;
  if (r < 64) v = (c < 64) ? wr[(r * 64 + c) * 9 + k] : -wi[(r * 64 + c - 64) * 9 + k];
  else {
    int r2 = r - 64;
    v = (c < 64) ? wi[(r2 * 64 + c) * 9 + k] : -wr[(r2 * 64 + c - 64) * 9 + k];
  }
  unsigned int u = __builtin_bit_cast(unsigned int, v);
  u = (u + 0x7fffu + ((u >> 16) & 1u)) >> 16;
  wc[t] = (unsigned short)u;
}

// ---------------------------------------------------------------------------
// Kernel 0b: build W2[9 taps][32 rows][192 chans] bf16 for the off/mag GEMM.
//   rows 0..17  : offset conv weights, chans 0..127  = concat(xr,xi) channels
//   rows 18..26 : mag conv weights,    chans 128..191 = |x| channels
//   everything else zero.
// ---------------------------------------------------------------------------
__global__ __launch_bounds__(256) void k_prepw2(
    const float* __restrict__ w_off, const float* __restrict__ w_mag,
    unsigned short* __restrict__ w2) {
  int t = blockIdx.x * 256 + threadIdx.x;   // 9*32*192 = 55296 exactly
  int c = t % 192;
  int r = (t / 192) % 32;
  int k = t / (192 * 32);
  float v = 0.f;
  if (r < 18 && c < 128) v = w_off[((size_t)r * 128 + c) * 9 + k];
  else if (r >= 18 && r < 27 && c >= 128) v = w_mag[((size_t)(r - 18) * 64 + (c - 128)) * 9 + k];
  unsigned int u = __builtin_bit_cast(unsigned int, v);
  u = (u + 0x7fffu + ((u >> 16) & 1u)) >> 16;
  w2[t] = (unsigned short)u;
}

// ---------------------------------------------------------------------------
// Kernel 1: offset conv (128ch -> 18ch) + magnitude conv (64ch -> 9ch,
// sigmoid) as one MFMA GEMM.  Block = 64 pixels of one row (b,h,wt half).
// Per ty in 0..2: stage input row y=h+ty-1 as S[66 cols][192 ch] bf16
// (XOR-swizzled, 512B col stride), then 3 tx taps x 2 m-tiles x 6 k-steps
// of mfma_16x16x32.  Wave g owns pixels [16g,16g+16), rows 0..31.
// ---------------------------------------------------------------------------
__global__ __launch_bounds__(256) void k_offmag(
    const float* __restrict__ xr, const float* __restrict__ xi,
    const unsigned short* __restrict__ W2,
    float* __restrict__ off_o, float* __restrict__ mag_o) {
  __shared__ unsigned short S[66 * 256];   // 66 cols * 512 B = 33 KB

  int blk = blockIdx.x;
  int wt = blk & 1;
  int h = (blk >> 1) & (HD - 1);
  int b = blk >> 8;
  int w0 = wt * 64;

  int tid = threadIdx.x;
  int lane = tid & 63;
  int g = tid >> 6;
  int l15 = lane & 15;
  int hi8 = (lane >> 4) * 8;

  const float* xrb = xr + (size_t)b * 64 * HW;
  const float* xib = xi + (size_t)b * 64 * HW;

  int sub = tid & 3;            // k-chunk owner within a column
  int colm = tid >> 2;          // 0..63
  int jm = colm + 1;            // LDS column (halo at 0 and 65)
  int wm = w0 + colm;           // always in range

  f32x4 acc[2];
  acc[0] = (f32x4)(0.f);
  acc[1] = (f32x4)(0.f);

#pragma unroll 1
  for (int ty = 0; ty < 3; ++ty) {
    int y = h + ty - 1;
    if ((unsigned)y >= (unsigned)HD) continue;   // zero-pad row: contributes 0
    __syncthreads();                              // protect S from prev taps
    int rb = y * WD;

    // ---- main columns: thread writes 24 u32 (48 chans) of its column ----
#pragma unroll
    for (int i = 0; i < 24; ++i) {
      int s = sub + i * 4;      // u32 index 0..95 (chans 2s,2s+1)
      float v0, v1;
      if (s < 32) {
        const float* p = xrb + (size_t)(2 * s) * HW + rb + wm;
        v0 = p[0]; v1 = p[HW];
      } else if (s < 64) {
        const float* p = xib + (size_t)(2 * s - 64) * HW + rb + wm;
        v0 = p[0]; v1 = p[HW];
      } else {
        int c = 2 * s - 128;
        const float* pr = xrb + (size_t)c * HW + rb + wm;
        const float* pi = xib + (size_t)c * HW + rb + wm;
        float a0 = pr[0], a1 = pr[HW];
        float b0 = pi[0], b1 = pi[HW];
        v0 = sqrtf(a0 * a0 + b0 * b0);
        v1 = sqrtf(a1 * a1 + b1 * b1);
      }
      *(unsigned int*)((char*)S + jm * 512 + ((4 * s) ^ ((jm & 7) << 4))) = pkbf(v0, v1);
    }

    // ---- halo columns j=0 (w0-1) and j=65 (w0+64) ----
    if (tid < 192) {
      int j = (tid < 96) ? 0 : 65;
      int s = (tid < 96) ? tid : tid - 96;
      int wg = (j == 0) ? (w0 - 1) : (w0 + 64);
      float v0 = 0.f, v1 = 0.f;
      if ((unsigned)wg < (unsigned)WD) {
        if (s < 32) {
          const float* p = xrb + (size_t)(2 * s) * HW + rb + wg;
          v0 = p[0]; v1 = p[HW];
        } else if (s < 64) {
          const float* p = xib + (size_t)(2 * s - 64) * HW + rb + wg;
          v0 = p[0]; v1 = p[HW];
        } else {
          int c = 2 * s - 128;
          const float* pr = xrb + (size_t)c * HW + rb + wg;
          const float* pi = xib + (size_t)c * HW + rb + wg;
          float a0 = pr[0], a1 = pr[HW];
          float b0 = pi[0], b1 = pi[HW];
          v0 = sqrtf(a0 * a0 + b0 * b0);
          v1 = sqrtf(a1 * a1 + b1 * b1);
        }
      }
      *(unsigned int*)((char*)S + j * 512 + ((4 * s) ^ ((j & 7) << 4))) = pkbf(v0, v1);
    }
    __syncthreads();

    // ---- 3 tx taps of MFMA on this row ----
#pragma unroll
    for (int tx = 0; tx < 3; ++tx) {
      const unsigned short* wtap = W2 + (size_t)(ty * 3 + tx) * 32 * 192;
      int j = g * 16 + l15 + tx;             // B column for this lane
      const char* bcol = (const char*)S + j * 512;
      int xo = (j & 7) << 4;
#pragma unroll
      for (int s = 0; s < 6; ++s) {
        s16x8 bf = *(const s16x8*)(bcol + ((s * 64 + hi8 * 2) ^ xo));
#pragma unroll
        for (int mt = 0; mt < 2; ++mt) {
          s16x8 af = *(const s16x8*)(wtap + (mt * 16 + l15) * 192 + s * 32 + hi8);
          acc[mt] = __builtin_amdgcn_mfma_f32_16x16x32_bf16(af, bf, acc[mt], 0, 0, 0);
        }
      }
    }
  }

  // ---- epilogue: rows 0..17 -> off, rows 18..26 -> sigmoid -> mag ----
  int p = h * WD + w0 + g * 16 + l15;
#pragma unroll
  for (int mt = 0; mt < 2; ++mt) {
#pragma unroll
    for (int r = 0; r < 4; ++r) {
      int row = mt * 16 + (lane >> 4) * 4 + r;
      float v = acc[mt][r];
      if (row < 18) off_o[((size_t)(b * 18 + row)) * HW + p] = v;
      else if (row < 27) mag_o[((size_t)(b * 9 + row - 18)) * HW + p] = 1.f / (1.f + expf(-v));
    }
  }
}

// ---------------------------------------------------------------------------
// Kernel 2: deformable sampling + complex contraction via bf16 MFMA.
// (unchanged from round 2 — verified)
// ---------------------------------------------------------------------------
__global__ __launch_bounds__(256) void k_main(
    const float* __restrict__ xr, const float* __restrict__ xi,
    const float* __restrict__ off_i, const float* __restrict__ mag_i,
    const unsigned short* __restrict__ Wc,
    const float* __restrict__ b_real, const float* __restrict__ b_imag,
    float* __restrict__ out) {
  __shared__ unsigned short S[64 * 128];   // 16 KB

  int blk = blockIdx.x;
  int wt = blk & 1;
  int h = (blk >> 1) & (HD - 1);
  int b = blk >> 8;
  int w0 = wt * 64;

  int tid = threadIdx.x;
  int lane = tid & 63;
  int g = tid >> 6;               // wave id 0..3
  int w = w0 + lane;              // this thread's sampling pixel
  int l15 = lane & 15;
  int hi8 = (lane >> 4) * 8;      // k-offset within fragment
  int xo = (l15 & 7) << 4;        // read-side XOR (row = tile*16 + l15)

  const float* xrb = xr + (size_t)b * 64 * HW;
  const float* xib = xi + (size_t)b * 64 * HW;
  int cbase = g * 32;             // channels this thread samples
  const float* xbase = (g < 2) ? (xrb + (size_t)cbase * HW)
                               : (xib + (size_t)(cbase - 64) * HW);
  int ppos = h * WD + w;

  f32x4 accR[4], accI[4];
#pragma unroll
  for (int t = 0; t < 4; ++t) {
    accR[t] = (f32x4)(0.f);
    accI[t] = (f32x4)(0.f);
  }

#pragma unroll 1
  for (int k = 0; k < 9; ++k) {
    // ---- per-pixel bilinear corner data ----
    float dy = off_i[((size_t)(b * 18 + 2 * k)) * HW + ppos];
    float dx = off_i[((size_t)(b * 18 + 2 * k + 1)) * HW + ppos];
    float m  = mag_i[((size_t)(b * 9 + k)) * HW + ppos];
    float py = (float)(h - 1 + k / 3) + dy;
    float px = (float)(w - 1 + k % 3) + dx;
    float y0f = floorf(py), x0f = floorf(px);
    float wy = py - y0f, wx = px - x0f;
    int y0 = (int)y0f, x0 = (int)x0f;

    float cw[4];
    cw[0] = (1.f - wy) * (1.f - wx) * m;
    cw[1] = (1.f - wy) * wx * m;
    cw[2] = wy * (1.f - wx) * m;
    cw[3] = wy * wx * m;
    int idx[4];
#pragma unroll
    for (int cc = 0; cc < 4; ++cc) {
      int yy = y0 + (cc >> 1);
      int xx = x0 + (cc & 1);
      bool ok = ((unsigned)yy < (unsigned)HD) && ((unsigned)xx < (unsigned)WD);
      if (!ok) cw[cc] = 0.f;
      int yc = yy < 0 ? 0 : (yy > HD - 1 ? HD - 1 : yy);
      int xc = xx < 0 ? 0 : (xx > WD - 1 ? WD - 1 : xx);
      idx[cc] = yc * WD + xc;
    }

    // ---- sample 32 channels at this pixel -> bf16 -> swizzled LDS row ----
#pragma unroll
    for (int q = 0; q < 4; ++q) {
      u32x4 wv;
#pragma unroll
      for (int j2 = 0; j2 < 4; ++j2) {
        const float* p0 = xbase + (size_t)(q * 8 + j2 * 2) * HW;
        const float* p1 = p0 + HW;
        float v0 = cw[0] * p0[idx[0]] + cw[1] * p0[idx[1]] +
                   cw[2] * p0[idx[2]] + cw[3] * p0[idx[3]];
        float v1 = cw[0] * p1[idx[0]] + cw[1] * p1[idx[1]] +
                   cw[2] * p1[idx[2]] + cw[3] * p1[idx[3]];
        wv[j2] = pkbf(v0, v1);
      }
      int bytecol = ((cbase + q * 8) * 2) ^ ((lane & 7) << 4);
      *(u32x4*)((char*)S + lane * 256 + bytecol) = wv;
    }

    // ---- A-fragments (weights, L2-hot) — issue before the barrier ----
    const unsigned short* wa = Wc + (size_t)k * 16384 + (g * 16 + l15) * 128 + hi8;
    s16x8 aR[4], aI[4];
#pragma unroll
    for (int s = 0; s < 4; ++s) {
      aR[s] = *(const s16x8*)(wa + s * 32);
      aI[s] = *(const s16x8*)(wa + 64 * 128 + s * 32);
    }

    __syncthreads();

    // ---- MFMA: 4 n-tiles x 4 k-steps, B shared between real/imag ----
#pragma unroll
    for (int t = 0; t < 4; ++t) {
      const char* brow = (const char*)S + (t * 16 + l15) * 256;
#pragma unroll
      for (int s = 0; s < 4; ++s) {
        s16x8 bf = *(const s16x8*)(brow + ((s * 64 + (hi8 << 1)) ^ xo));
        accR[t] = __builtin_amdgcn_mfma_f32_16x16x32_bf16(aR[s], bf, accR[t], 0, 0, 0);
        accI[t] = __builtin_amdgcn_mfma_f32_16x16x32_bf16(aI[s], bf, accI[t], 0, 0, 0);
      }
    }
    __syncthreads();
  }

  // ---- epilogue: bias + coalesced float2 stores ----
  float2* outp = (float2*)out;
#pragma unroll
  for (int r = 0; r < 4; ++r) {
    int o = g * 16 + (lane >> 4) * 4 + r;
    float br = b_real[o] - b_imag[o];
#pragma unroll
    for (int t = 0; t < 4; ++t) {
      int pe = h * WD + w0 + t * 16 + l15;
      float2 v;
      v.x = accR[t][r] + br;
      v.y = accI[t][r] - br;
      outp[((size_t)(b * 64 + o)) * HW + pe] = v;
    }
  }
}

// ---------------------------------------------------------------------------
extern "C" void kernel_launch(void* const* d_in, const int* in_sizes, int n_in,
                              void* d_out, int out_size, void* d_ws, size_t ws_size,
                              hipStream_t stream) {
  const float* xr     = (const float*)d_in[0];
  const float* xi     = (const float*)d_in[1];
  const float* w_off  = (const float*)d_in[2];
  const float* w_mag  = (const float*)d_in[3];
  const float* w_real = (const float*)d_in[4];
  const float* w_imag = (const float*)d_in[5];
  const float* b_real = (const float*)d_in[6];
  const float* b_imag = (const float*)d_in[7];
  float* out = (float*)d_out;

  float* ws = (float*)d_ws;
  float* off_ws = ws;                              // 8*18*16384 = 2359296 f
  float* mag_ws = off_ws + 2359296;                // 8*9*16384  = 1179648 f
  unsigned short* Wc = (unsigned short*)(mag_ws + 1179648); // 9*128*128 bf16
  unsigned short* W2 = Wc + 9 * 128 * 128;         // 9*32*192 bf16

  hipLaunchKernelGGL(k_prepw, dim3(576), dim3(256), 0, stream,
                     w_real, w_imag, Wc);
  hipLaunchKernelGGL(k_prepw2, dim3(216), dim3(256), 0, stream,
                     w_off, w_mag, W2);
  hipLaunchKernelGGL(k_offmag, dim3(2048), dim3(256), 0, stream,
                     xr, xi, W2, off_ws, mag_ws);
  hipLaunchKernelGGL(k_main, dim3(2048), dim3(256), 0, stream,
                     xr, xi, off_ws, mag_ws, Wc, b_real, b_imag, out);
}

// Round 4
// 549.944 us; speedup vs baseline: 1.9802x; 1.1292x over previous
//
#include <hip/hip_runtime.h>
#include <math.h>

#define HD 128
#define WD 128
#define HW (HD*WD)

typedef __attribute__((ext_vector_type(8))) short s16x8;     // 8 bf16 (4 VGPRs)
typedef __attribute__((ext_vector_type(4))) float f32x4;     // MFMA acc
typedef __attribute__((ext_vector_type(4))) unsigned int u32x4;

// round-to-nearest-even f32 -> bf16 bits, packed pair
__device__ inline unsigned int pkbf(float a, float b) {
  unsigned int ua = __builtin_bit_cast(unsigned int, a);
  unsigned int ub = __builtin_bit_cast(unsigned int, b);
  ua = (ua + 0x7fffu + ((ua >> 16) & 1u)) >> 16;
  ub = (ub + 0x7fffu + ((ub >> 16) & 1u)) >> 16;
  return ua | (ub << 16);
}

// ---------------------------------------------------------------------------
// Kernel 0a: build Wcomb[9][128][128] bf16 for the main contraction.
//   r<64 :  c<64 ? Wr[r][c][k]    : -Wi[r][c-64][k]      (real output rows)
//   r>=64:  c<64 ? Wi[r-64][c][k] : -Wr[r-64][c-64][k]   (imag output rows)
// ---------------------------------------------------------------------------
__global__ __launch_bounds__(256) void k_prepw(
    const float* __restrict__ wr, const float* __restrict__ wi,
    unsigned short* __restrict__ wc) {
  int t = blockIdx.x * 256 + threadIdx.x;
  if (t >= 9 * 128 * 128) return;
  int c = t & 127;
  int r = (t >> 7) & 127;
  int k = t >> 14;
  float v;
  if (r < 64) v = (c < 64) ? wr[(r * 64 + c) * 9 + k] : -wi[(r * 64 + c - 64) * 9 + k];
  else {
    int r2 = r - 64;
    v = (c < 64) ? wi[(r2 * 64 + c) * 9 + k] : -wr[(r2 * 64 + c - 64) * 9 + k];
  }
  unsigned int u = __builtin_bit_cast(unsigned int, v);
  u = (u + 0x7fffu + ((u >> 16) & 1u)) >> 16;
  wc[t] = (unsigned short)u;
}

// ---------------------------------------------------------------------------
// Kernel 0b: build W2[9 taps][32 rows][192 chans] bf16 for the off/mag GEMM.
// ---------------------------------------------------------------------------
__global__ __launch_bounds__(256) void k_prepw2(
    const float* __restrict__ w_off, const float* __restrict__ w_mag,
    unsigned short* __restrict__ w2) {
  int t = blockIdx.x * 256 + threadIdx.x;   // 9*32*192 = 55296 exactly
  int c = t % 192;
  int r = (t / 192) % 32;
  int k = t / (192 * 32);
  float v = 0.f;
  if (r < 18 && c < 128) v = w_off[((size_t)r * 128 + c) * 9 + k];
  else if (r >= 18 && r < 27 && c >= 128) v = w_mag[((size_t)(r - 18) * 64 + (c - 128)) * 9 + k];
  unsigned int u = __builtin_bit_cast(unsigned int, v);
  u = (u + 0x7fffu + ((u >> 16) & 1u)) >> 16;
  w2[t] = (unsigned short)u;
}

// ---------------------------------------------------------------------------
// Kernel 1: offset+mag convs as one MFMA GEMM (unchanged structure; block
// decode is now XCD-affine: image b pinned to XCD b for L2 locality).
// ---------------------------------------------------------------------------
__global__ __launch_bounds__(256) void k_offmag(
    const float* __restrict__ xr, const float* __restrict__ xi,
    const unsigned short* __restrict__ W2,
    float* __restrict__ off_o, float* __restrict__ mag_o) {
  __shared__ unsigned short S[66 * 256];   // 66 cols * 512 B = 33 KB

  int blk = blockIdx.x;
  int b = blk & 7;                 // XCD-affine
  int rest = blk >> 3;
  int wt = rest & 1;
  int h = rest >> 1;
  int w0 = wt * 64;

  int tid = threadIdx.x;
  int lane = tid & 63;
  int g = tid >> 6;
  int l15 = lane & 15;
  int hi8 = (lane >> 4) * 8;

  const float* xrb = xr + (size_t)b * 64 * HW;
  const float* xib = xi + (size_t)b * 64 * HW;

  int sub = tid & 3;            // k-chunk owner within a column
  int colm = tid >> 2;          // 0..63
  int jm = colm + 1;            // LDS column (halo at 0 and 65)
  int wm = w0 + colm;           // always in range

  f32x4 acc[2];
  acc[0] = (f32x4)(0.f);
  acc[1] = (f32x4)(0.f);

#pragma unroll 1
  for (int ty = 0; ty < 3; ++ty) {
    int y = h + ty - 1;
    if ((unsigned)y >= (unsigned)HD) continue;   // zero-pad row: contributes 0
    __syncthreads();                              // protect S from prev taps
    int rb = y * WD;

    // ---- main columns: thread writes 24 u32 (48 chans) of its column ----
#pragma unroll
    for (int i = 0; i < 24; ++i) {
      int s = sub + i * 4;      // u32 index 0..95 (chans 2s,2s+1)
      float v0, v1;
      if (s < 32) {
        const float* p = xrb + (size_t)(2 * s) * HW + rb + wm;
        v0 = p[0]; v1 = p[HW];
      } else if (s < 64) {
        const float* p = xib + (size_t)(2 * s - 64) * HW + rb + wm;
        v0 = p[0]; v1 = p[HW];
      } else {
        int c = 2 * s - 128;
        const float* pr = xrb + (size_t)c * HW + rb + wm;
        const float* pi = xib + (size_t)c * HW + rb + wm;
        float a0 = pr[0], a1 = pr[HW];
        float b0 = pi[0], b1 = pi[HW];
        v0 = sqrtf(a0 * a0 + b0 * b0);
        v1 = sqrtf(a1 * a1 + b1 * b1);
      }
      *(unsigned int*)((char*)S + jm * 512 + ((4 * s) ^ ((jm & 7) << 4))) = pkbf(v0, v1);
    }

    // ---- halo columns j=0 (w0-1) and j=65 (w0+64) ----
    if (tid < 192) {
      int j = (tid < 96) ? 0 : 65;
      int s = (tid < 96) ? tid : tid - 96;
      int wg = (j == 0) ? (w0 - 1) : (w0 + 64);
      float v0 = 0.f, v1 = 0.f;
      if ((unsigned)wg < (unsigned)WD) {
        if (s < 32) {
          const float* p = xrb + (size_t)(2 * s) * HW + rb + wg;
          v0 = p[0]; v1 = p[HW];
        } else if (s < 64) {
          const float* p = xib + (size_t)(2 * s - 64) * HW + rb + wg;
          v0 = p[0]; v1 = p[HW];
        } else {
          int c = 2 * s - 128;
          const float* pr = xrb + (size_t)c * HW + rb + wg;
          const float* pi = xib + (size_t)c * HW + rb + wg;
          float a0 = pr[0], a1 = pr[HW];
          float b0 = pi[0], b1 = pi[HW];
          v0 = sqrtf(a0 * a0 + b0 * b0);
          v1 = sqrtf(a1 * a1 + b1 * b1);
        }
      }
      *(unsigned int*)((char*)S + j * 512 + ((4 * s) ^ ((j & 7) << 4))) = pkbf(v0, v1);
    }
    __syncthreads();

    // ---- 3 tx taps of MFMA on this row ----
#pragma unroll
    for (int tx = 0; tx < 3; ++tx) {
      const unsigned short* wtap = W2 + (size_t)(ty * 3 + tx) * 32 * 192;
      int j = g * 16 + l15 + tx;             // B column for this lane
      const char* bcol = (const char*)S + j * 512;
      int xo = (j & 7) << 4;
#pragma unroll
      for (int s = 0; s < 6; ++s) {
        s16x8 bf = *(const s16x8*)(bcol + ((s * 64 + hi8 * 2) ^ xo));
#pragma unroll
        for (int mt = 0; mt < 2; ++mt) {
          s16x8 af = *(const s16x8*)(wtap + (mt * 16 + l15) * 192 + s * 32 + hi8);
          acc[mt] = __builtin_amdgcn_mfma_f32_16x16x32_bf16(af, bf, acc[mt], 0, 0, 0);
        }
      }
    }
  }

  // ---- epilogue: rows 0..17 -> off, rows 18..26 -> sigmoid -> mag ----
  int p = h * WD + w0 + g * 16 + l15;
#pragma unroll
  for (int mt = 0; mt < 2; ++mt) {
#pragma unroll
    for (int r = 0; r < 4; ++r) {
      int row = mt * 16 + (lane >> 4) * 4 + r;
      float v = acc[mt][r];
      if (row < 18) off_o[((size_t)(b * 18 + row)) * HW + p] = v;
      else if (row < 27) mag_o[((size_t)(b * 9 + row - 18)) * HW + p] = 1.f / (1.f + expf(-v));
    }
  }
}

// ---------------------------------------------------------------------------
// Kernel 2: deformable sampling + complex contraction via bf16 MFMA.
// v3: 3 taps staged per barrier pair (48 KB LDS), 16-slot XOR swizzle,
// XCD-affine block decode (image b -> XCD b).
// ---------------------------------------------------------------------------
__global__ __launch_bounds__(256) void k_main(
    const float* __restrict__ xr, const float* __restrict__ xi,
    const float* __restrict__ off_i, const float* __restrict__ mag_i,
    const unsigned short* __restrict__ Wc,
    const float* __restrict__ b_real, const float* __restrict__ b_imag,
    float* __restrict__ out) {
  __shared__ unsigned short S[3 * 64 * 128];   // 48 KB: S[tap3][pix][chan]

  int blk = blockIdx.x;
  int b = blk & 7;                 // XCD-affine
  int rest = blk >> 3;
  int wt = rest & 1;
  int h = rest >> 1;
  int w0 = wt * 64;

  int tid = threadIdx.x;
  int lane = tid & 63;
  int g = tid >> 6;               // wave id 0..3
  int w = w0 + lane;              // this thread's sampling pixel
  int l15 = lane & 15;
  int hi8 = (lane >> 4) * 8;      // k-offset within fragment
  int xo = l15 << 4;              // read-side XOR (row&15 == l15)
  int swz = (lane & 15) << 4;     // write-side XOR (row == lane)

  const float* xrb = xr + (size_t)b * 64 * HW;
  const float* xib = xi + (size_t)b * 64 * HW;
  int cbase = g * 32;             // channels this thread samples
  const float* xbase = (g < 2) ? (xrb + (size_t)cbase * HW)
                               : (xib + (size_t)(cbase - 64) * HW);
  int ppos = h * WD + w;

  f32x4 accR[4], accI[4];
#pragma unroll
  for (int t = 0; t < 4; ++t) {
    accR[t] = (f32x4)(0.f);
    accI[t] = (f32x4)(0.f);
  }

#pragma unroll 1
  for (int kt = 0; kt < 3; ++kt) {
    __syncthreads();              // S free: prev MFMA phase done

    // ======== gather phase: stage taps kt*3 .. kt*3+2 ========
#pragma unroll 1
    for (int k3 = 0; k3 < 3; ++k3) {
      int k = kt * 3 + k3;
      float dy = off_i[((size_t)(b * 18 + 2 * k)) * HW + ppos];
      float dx = off_i[((size_t)(b * 18 + 2 * k + 1)) * HW + ppos];
      float m  = mag_i[((size_t)(b * 9 + k)) * HW + ppos];
      float py = (float)(h - 1 + k / 3) + dy;
      float px = (float)(w - 1 + k % 3) + dx;
      float y0f = floorf(py), x0f = floorf(px);
      float wy = py - y0f, wx = px - x0f;
      int y0 = (int)y0f, x0 = (int)x0f;

      float cw[4];
      cw[0] = (1.f - wy) * (1.f - wx) * m;
      cw[1] = (1.f - wy) * wx * m;
      cw[2] = wy * (1.f - wx) * m;
      cw[3] = wy * wx * m;
      int idx[4];
#pragma unroll
      for (int cc = 0; cc < 4; ++cc) {
        int yy = y0 + (cc >> 1);
        int xx = x0 + (cc & 1);
        bool ok = ((unsigned)yy < (unsigned)HD) && ((unsigned)xx < (unsigned)WD);
        if (!ok) cw[cc] = 0.f;
        int yc = yy < 0 ? 0 : (yy > HD - 1 ? HD - 1 : yy);
        int xc = xx < 0 ? 0 : (xx > WD - 1 ? WD - 1 : xx);
        idx[cc] = yc * WD + xc;
      }

      char* sbase = (char*)S + k3 * 16384 + lane * 256;
#pragma unroll
      for (int q = 0; q < 4; ++q) {
        u32x4 wv;
#pragma unroll
        for (int j2 = 0; j2 < 4; ++j2) {
          const float* p0 = xbase + (size_t)(q * 8 + j2 * 2) * HW;
          const float* p1 = p0 + HW;
          float v0 = cw[0] * p0[idx[0]] + cw[1] * p0[idx[1]] +
                     cw[2] * p0[idx[2]] + cw[3] * p0[idx[3]];
          float v1 = cw[0] * p1[idx[0]] + cw[1] * p1[idx[1]] +
                     cw[2] * p1[idx[2]] + cw[3] * p1[idx[3]];
          wv[j2] = pkbf(v0, v1);
        }
        *(u32x4*)(sbase + ((cbase * 2 + q * 16) ^ swz)) = wv;
      }
    }
    __syncthreads();

    // ======== MFMA phase: 3 taps x 4 n-tiles x 4 k-steps ========
#pragma unroll
    for (int k3 = 0; k3 < 3; ++k3) {
      int k = kt * 3 + k3;
      const unsigned short* wa = Wc + (size_t)k * 16384 + (g * 16 + l15) * 128 + hi8;
      s16x8 aR[4], aI[4];
#pragma unroll
      for (int s = 0; s < 4; ++s) {
        aR[s] = *(const s16x8*)(wa + s * 32);
        aI[s] = *(const s16x8*)(wa + 64 * 128 + s * 32);
      }
      const char* stap = (const char*)S + k3 * 16384;
#pragma unroll
      for (int t = 0; t < 4; ++t) {
        const char* brow = stap + (t * 16 + l15) * 256;
#pragma unroll
        for (int s = 0; s < 4; ++s) {
          s16x8 bf = *(const s16x8*)(brow + ((s * 64 + (hi8 << 1)) ^ xo));
          accR[t] = __builtin_amdgcn_mfma_f32_16x16x32_bf16(aR[s], bf, accR[t], 0, 0, 0);
          accI[t] = __builtin_amdgcn_mfma_f32_16x16x32_bf16(aI[s], bf, accI[t], 0, 0, 0);
        }
      }
    }
  }

  // ---- epilogue: bias + coalesced float2 stores ----
  float2* outp = (float2*)out;
#pragma unroll
  for (int r = 0; r < 4; ++r) {
    int o = g * 16 + (lane >> 4) * 4 + r;
    float br = b_real[o] - b_imag[o];
#pragma unroll
    for (int t = 0; t < 4; ++t) {
      int pe = h * WD + w0 + t * 16 + l15;
      float2 v;
      v.x = accR[t][r] + br;
      v.y = accI[t][r] - br;
      outp[((size_t)(b * 64 + o)) * HW + pe] = v;
    }
  }
}

// ---------------------------------------------------------------------------
extern "C" void kernel_launch(void* const* d_in, const int* in_sizes, int n_in,
                              void* d_out, int out_size, void* d_ws, size_t ws_size,
                              hipStream_t stream) {
  const float* xr     = (const float*)d_in[0];
  const float* xi     = (const float*)d_in[1];
  const float* w_off  = (const float*)d_in[2];
  const float* w_mag  = (const float*)d_in[3];
  const float* w_real = (const float*)d_in[4];
  const float* w_imag = (const float*)d_in[5];
  const float* b_real = (const float*)d_in[6];
  const float* b_imag = (const float*)d_in[7];
  float* out = (float*)d_out;

  float* ws = (float*)d_ws;
  float* off_ws = ws;                              // 8*18*16384 = 2359296 f
  float* mag_ws = off_ws + 2359296;                // 8*9*16384  = 1179648 f
  unsigned short* Wc = (unsigned short*)(mag_ws + 1179648); // 9*128*128 bf16
  unsigned short* W2 = Wc + 9 * 128 * 128;         // 9*32*192 bf16

  hipLaunchKernelGGL(k_prepw, dim3(576), dim3(256), 0, stream,
                     w_real, w_imag, Wc);
  hipLaunchKernelGGL(k_prepw2, dim3(216), dim3(256), 0, stream,
                     w_off, w_mag, W2);
  hipLaunchKernelGGL(k_offmag, dim3(2048), dim3(256), 0, stream,
                     xr, xi, W2, off_ws, mag_ws);
  hipLaunchKernelGGL(k_main, dim3(2048), dim3(256), 0, stream,
                     xr, xi, off_ws, mag_ws, Wc, b_real, b_imag, out);
}